// Round 10
// baseline (56.282 us; speedup 1.0000x reference)
//
#include <hip/hip_runtime.h>
#include <cmath>

#define B_ 4
#define N_ 512
#define F_ 128
#define BN_ (B_*N_)   // 2048
#define NG_ (BN_/4)   // 512 row-groups of 4

__device__ __forceinline__ float elu_f(float x) {
    return fmaxf(x, __expf(fminf(x, 0.f)) - 1.f);
}

// ---------------------------------------------------------------------------
// Kernel 1 (heterogeneous grid, 1536 blocks x 512 thr):
//  blocks [0,512):    lin1 for 4 rows — Hi = H@dW1[:F]+db1, EHi = exp(Hi),
//                     HjT[b][f][n] = (H@dW1[F:])^T. K split across kq=t>>7.
//  blocks [512,1536): nbr partial for 4 rows x one j-half (256 j's):
//                     nfh[jh][row][f] = undivided masked column sum,
//                     degh[jh][row]   = partial A>0 count.
// ---------------------------------------------------------------------------
__global__ __launch_bounds__(512, 8) void k_pre(
    const float* __restrict__ H, const float* __restrict__ A,
    const float* __restrict__ dW1, const float* __restrict__ db1,
    float* __restrict__ Hi, float* __restrict__ EHi, float* __restrict__ HjT,
    float* __restrict__ nfh, float* __restrict__ degh) {
    __shared__ float sH[4][F_];
    __shared__ float sPA[3][4][F_], sPB[3][4][F_];
    __shared__ float sN[3][4][F_];
    __shared__ int   sDeg[4][4];
    const int t = threadIdx.x;
    const int f = t & 127;
    const int kq = t >> 7;                 // K-quarter (lin1) / j-quarter (nbr)
    const int lane = t & 63;
    const int w = t >> 6;

    if (blockIdx.x < NG_) {
        // ---------------- lin1 ----------------
        const int row0 = blockIdx.x * 4;
        const int b  = row0 >> 9;
        const int n0 = row0 & 511;
        sH[kq][f] = H[(size_t)(row0 + kq) * F_ + f];
        __syncthreads();
        float accA[4] = {0.f,0.f,0.f,0.f}, accB[4] = {0.f,0.f,0.f,0.f};
        const int k0 = kq * 32;
        #pragma unroll 4
        for (int k = k0; k < k0 + 32; ++k) {
            const float wa = dW1[(size_t)k * F_ + f];
            const float wb = dW1[(size_t)(F_ + k) * F_ + f];
            #pragma unroll
            for (int r = 0; r < 4; ++r) {
                accA[r] = fmaf(sH[r][k], wa, accA[r]);
                accB[r] = fmaf(sH[r][k], wb, accB[r]);
            }
        }
        if (kq > 0) {
            #pragma unroll
            for (int r = 0; r < 4; ++r) {
                sPA[kq - 1][r][f] = accA[r];
                sPB[kq - 1][r][f] = accB[r];
            }
        }
        __syncthreads();
        if (kq == 0) {
            const float bias = db1[f];
            float bsum[4];
            #pragma unroll
            for (int r = 0; r < 4; ++r) {
                const float av = accA[r] + sPA[0][r][f] + sPA[1][r][f]
                               + sPA[2][r][f] + bias;
                Hi [(size_t)(row0 + r) * F_ + f] = av;
                EHi[(size_t)(row0 + r) * F_ + f] = __expf(av);
                bsum[r] = accB[r] + sPB[0][r][f] + sPB[1][r][f] + sPB[2][r][f];
            }
            float4 hv;
            hv.x = bsum[0]; hv.y = bsum[1]; hv.z = bsum[2]; hv.w = bsum[3];
            *reinterpret_cast<float4*>(HjT + ((size_t)b * F_ + f) * N_ + n0) = hv;
        }
    } else {
        // ---------------- nbr (one j-half) ----------------
        const int bx = blockIdx.x - NG_;   // 0..1023
        const int g  = bx >> 1;            // row-group
        const int jh = bx & 1;             // j-half
        const int row0 = g * 4;
        const int b = row0 >> 9;
        const int jbase = jh * 256 + kq * 64;

        unsigned long long msk[4];
        #pragma unroll
        for (int r = 0; r < 4; ++r)
            msk[r] = __ballot(A[(size_t)(row0 + r) * N_ + jbase + lane] > 0.f);
        if (lane == 0 && (w & 1) == 0) {
            #pragma unroll
            for (int r = 0; r < 4; ++r) sDeg[kq][r] = __popcll(msk[r]);
        }

        float accN[4] = {0.f,0.f,0.f,0.f};
        const float* hb = H + ((size_t)b * N_ + jbase) * F_ + f;
        #pragma unroll 8
        for (int j = 0; j < 64; ++j) {
            const float h = hb[(size_t)j * F_];
            #pragma unroll
            for (int r = 0; r < 4; ++r) {
                const float m = ((msk[r] >> j) & 1ull) ? 1.f : 0.f;
                accN[r] = fmaf(m, h, accN[r]);
            }
        }
        if (kq > 0) {
            #pragma unroll
            for (int r = 0; r < 4; ++r) sN[kq - 1][r][f] = accN[r];
        }
        __syncthreads();
        if (kq == 0) {
            #pragma unroll
            for (int r = 0; r < 4; ++r) {
                const float s = accN[r] + sN[0][r][f] + sN[1][r][f] + sN[2][r][f];
                nfh[((size_t)jh * BN_ + row0 + r) * F_ + f] = s;
            }
        }
        if (t < 4)
            degh[(size_t)jh * BN_ + row0 + t] =
                (float)(sDeg[0][t] + sDeg[1][t] + sDeg[2][t] + sDeg[3][t]);
    }
}

// ---------------------------------------------------------------------------
// Kernel 2: score. 2 rows/block, 1024 blocks x 512 thr (thread = j).
// elu(hi+hj) = med3(x, Ei*Ej-1, 0): 4 VALU ops/element, exp shared by rows.
// Uniform operands staged in LDS (broadcast reads); hj double-buffered.
// ---------------------------------------------------------------------------
__global__ __launch_bounds__(512, 8) void k_score(
    const float* __restrict__ Hi, const float* __restrict__ EHi,
    const float* __restrict__ HjT, const float* __restrict__ A,
    const float* __restrict__ dW2, const float* __restrict__ db2,
    float* __restrict__ maxcv, float* __restrict__ maskout) {
    __shared__ float4 sU[32][5];          // [quad][0,1]=hi; [2,3]=Ei; [4]=w
    __shared__ float red_mx[8][2];
    const int t = threadIdx.x;            // == j
    const int lane = t & 63;
    const int w = t >> 6;
    const int row0 = blockIdx.x * 2;
    const int b = row0 >> 9;

    if (t < 160) {
        const int q  = t / 5;
        const int sl = t - q * 5;
        const float* src = (sl < 2) ? (Hi  + (size_t)(row0 + sl)     * F_ + 4 * q)
                         : (sl < 4) ? (EHi + (size_t)(row0 + sl - 2) * F_ + 4 * q)
                                    : (dW2 + 4 * q);
        sU[q][sl] = *reinterpret_cast<const float4*>(src);
    }
    const float a0 = A[(size_t)row0 * N_ + t];
    const float a1 = A[(size_t)(row0 + 1) * N_ + t];

    const float* __restrict__ hjp = HjT + (size_t)b * F_ * N_ + t;
    float hjA[4], hjB[4];
    #pragma unroll
    for (int s = 0; s < 4; ++s) hjA[s] = hjp[(size_t)s * N_];
    __syncthreads();

    float acc0 = 0.f, acc1 = 0.f;
    auto compQ = [&](int q, const float (&hjv)[4]) {
        const float4 h0 = sU[q][0], h1 = sU[q][1];
        const float4 e0 = sU[q][2], e1 = sU[q][3];
        const float4 wq = sU[q][4];
        const float* h0p = &h0.x; const float* h1p = &h1.x;
        const float* e0p = &e0.x; const float* e1p = &e1.x;
        const float* wqp = &wq.x;
        #pragma unroll
        for (int s = 0; s < 4; ++s) {
            const float hj = hjv[s];
            const float ej = __expf(hj);
            const float wv = wqp[s];
            const float x0 = h0p[s] + hj;
            const float p0 = fmaf(e0p[s], ej, -1.f);
            acc0 = fmaf(__builtin_amdgcn_fmed3f(x0, p0, 0.f), wv, acc0);
            const float x1 = h1p[s] + hj;
            const float p1 = fmaf(e1p[s], ej, -1.f);
            acc1 = fmaf(__builtin_amdgcn_fmed3f(x1, p1, 0.f), wv, acc1);
        }
    };
    auto loadhj = [&](int q, float (&buf)[4]) {
        #pragma unroll
        for (int s = 0; s < 4; ++s) buf[s] = hjp[(size_t)(4 * q + s) * N_];
    };
    for (int q = 0; q < 32; q += 2) {
        loadhj(q + 1, hjB);
        compQ(q, hjA);
        if (q + 2 < 32) loadhj(q + 2, hjA);
        compQ(q + 1, hjB);
    }

    float mx0 = (a0 > 0.1f) ? acc0 : -INFINITY;
    float mx1 = (a1 > 0.1f) ? acc1 : -INFINITY;
    #pragma unroll
    for (int off = 1; off < 64; off <<= 1) {
        mx0 = fmaxf(mx0, __shfl_xor(mx0, off));
        mx1 = fmaxf(mx1, __shfl_xor(mx1, off));
    }
    if (lane == 0) { red_mx[w][0] = mx0; red_mx[w][1] = mx1; }
    __syncthreads();
    if (t < 2) {
        float m = -INFINITY;
        #pragma unroll
        for (int ww = 0; ww < 8; ++ww) m = fmaxf(m, red_mx[ww][t]);
        const float mc = (m > -INFINITY)
                       ? 1.f / (1.f + __expf(-(m + db2[0]))) : 0.f;
        maxcv[row0 + t] = mc;
        maskout[row0 + t] = (mc > 0.5f) ? 1.f : 0.f;
    }
}

// ---------------------------------------------------------------------------
// Kernel 3: row MLP. 4 rows/block, 512 blocks x 512 thr; f=t&127, kq=t>>7.
// nf assembled from the two undivided halves; deg = sum of halves.
// ---------------------------------------------------------------------------
__global__ __launch_bounds__(512, 4) void k_mlp(
    const float* __restrict__ H, const float* __restrict__ nfh,
    const float* __restrict__ degh, const float* __restrict__ maxcv,
    const float* __restrict__ rW1, const float* __restrict__ rb1,
    const float* __restrict__ rW2, const float* __restrict__ rb2,
    float* __restrict__ out) {
    __shared__ float sC[4][260];
    __shared__ float sP[3][4][F_];
    __shared__ float sL1[4][F_];
    __shared__ float sMC[4], sDegF[4];
    const int t  = threadIdx.x;
    const int f  = t & 127;
    const int kq = t >> 7;
    const int row0 = blockIdx.x * 4;

    {   // stage: H part + nf (sum halves / deg) — thread's row = kq
        const int row = row0 + kq;
        sC[kq][f] = H[(size_t)row * F_ + f];
        const float d = degh[row] + degh[BN_ + row];
        const float s = nfh[(size_t)row * F_ + f]
                      + nfh[(size_t)(BN_ + row) * F_ + f];
        sC[kq][F_ + f] = s / fmaxf(d, 1.f);
    }
    if (t < 4) {
        sMC[t]   = maxcv[row0 + t];
        sDegF[t] = degh[row0 + t] + degh[BN_ + row0 + t];
    }
    __syncthreads();

    // ---- layer 1 ----
    float macc[4];
    {
        const float bias = rb1[f];
        #pragma unroll
        for (int r = 0; r < 4; ++r) macc[r] = (kq == 0) ? bias : 0.f;
    }
    const int k0 = kq * 64;
    #pragma unroll 4
    for (int k = k0; k < k0 + 64; ++k) {
        const float wv = rW1[(size_t)k * F_ + f];
        #pragma unroll
        for (int r = 0; r < 4; ++r) macc[r] = fmaf(sC[r][k], wv, macc[r]);
    }
    if (kq == 3) {
        const float w256 = rW1[(size_t)256 * F_ + f];
        #pragma unroll
        for (int r = 0; r < 4; ++r) macc[r] = fmaf(sMC[r], w256, macc[r]);
    }
    if (kq > 0) {
        #pragma unroll
        for (int r = 0; r < 4; ++r) sP[kq - 1][r][f] = macc[r];
    }
    __syncthreads();
    if (kq == 0) {
        #pragma unroll
        for (int r = 0; r < 4; ++r)
            sL1[r][f] = elu_f(macc[r] + sP[0][r][f] + sP[1][r][f] + sP[2][r][f]);
    }
    __syncthreads();

    // ---- layer 2 ----
    float macc2[4];
    {
        const float bias2 = rb2[f];
        #pragma unroll
        for (int r = 0; r < 4; ++r) macc2[r] = (kq == 0) ? bias2 : 0.f;
    }
    const int m0k = kq * 32;
    #pragma unroll 4
    for (int k = m0k; k < m0k + 32; ++k) {
        const float wv = rW2[(size_t)k * F_ + f];
        #pragma unroll
        for (int r = 0; r < 4; ++r) macc2[r] = fmaf(sL1[r][k], wv, macc2[r]);
    }
    if (kq > 0) {
        #pragma unroll
        for (int r = 0; r < 4; ++r) sP[kq - 1][r][f] = macc2[r];
    }
    __syncthreads();
    if (kq == 0) {
        #pragma unroll
        for (int r = 0; r < 4; ++r) {
            const int row = row0 + r;
            const float res = macc2[r] + sP[0][r][f] + sP[1][r][f] + sP[2][r][f];
            const bool upd = (sMC[r] > 0.5f) && (sDegF[r] > 0.f);
            out[(size_t)row * F_ + f] = upd ? res : sC[r][f];
        }
    }
}

// ---------------------------------------------------------------------------
extern "C" void kernel_launch(void* const* d_in, const int* in_sizes, int n_in,
                              void* d_out, int out_size, void* d_ws, size_t ws_size,
                              hipStream_t stream) {
    const float* H   = (const float*)d_in[0];
    const float* A   = (const float*)d_in[1];
    const float* dW1 = (const float*)d_in[2];
    const float* db1 = (const float*)d_in[3];
    const float* dW2 = (const float*)d_in[4];
    const float* db2 = (const float*)d_in[5];
    const float* rW1 = (const float*)d_in[6];
    const float* rb1 = (const float*)d_in[7];
    const float* rW2 = (const float*)d_in[8];
    const float* rb2 = (const float*)d_in[9];

    float* ws   = (float*)d_ws;
    float* Hi   = ws;                      // [BN][F]
    float* EHi  = Hi   + BN_ * F_;         // [BN][F]
    float* HjT  = EHi  + BN_ * F_;         // [B][F][N]
    float* nfh  = HjT  + BN_ * F_;         // [2][BN][F] undivided halves
    float* degh = nfh  + 2 * BN_ * F_;     // [2][BN]
    float* maxc = degh + 2 * BN_;          // [BN]

    float* out      = (float*)d_out;       // [BN][F]
    float* mask_out = out + BN_ * F_;      // [BN]

    k_pre  <<<NG_ + 2 * NG_, 512, 0, stream>>>(H, A, dW1, db1,
                                               Hi, EHi, HjT, nfh, degh);
    k_score<<<BN_ / 2, 512, 0, stream>>>(Hi, EHi, HjT, A, dW2, db2,
                                         maxc, mask_out);
    k_mlp  <<<BN_ / 4, 512, 0, stream>>>(H, nfh, degh, maxc,
                                         rW1, rb1, rW2, rb2, out);
}

// Round 11
// 40.124 us; speedup vs baseline: 1.4027x; 1.4027x over previous
//
#include <hip/hip_runtime.h>
#include <cmath>

#define B_ 4
#define N_ 512
#define F_ 128
#define BN_ (B_*N_)   // 2048
#define NG_ (BN_/4)   // 512 row-groups of 4

__device__ __forceinline__ float elu_f(float x) {
    return fmaxf(x, __expf(fminf(x, 0.f)) - 1.f);
}

// ---------------------------------------------------------------------------
// Kernel 1 (544 blocks x 512 thr):
//  blocks [0,512):   lin1 for 4 rows — Hi = H@dW1[:F]+db1, EHi = exp(Hi),
//                    HjT[b][f][n] = (H@dW1[F:])^T. K split across kq=t>>7.
//  blocks [512,544): colsum partials: csp[b][e][f] = sum of 64 H rows.
// ---------------------------------------------------------------------------
__global__ __launch_bounds__(512, 4) void k_pre(
    const float* __restrict__ H, const float* __restrict__ dW1,
    const float* __restrict__ db1,
    float* __restrict__ Hi, float* __restrict__ EHi, float* __restrict__ HjT,
    float* __restrict__ csp) {
    __shared__ float sH[4][F_];
    __shared__ float sPA[3][4][F_], sPB[3][4][F_];
    const int t = threadIdx.x;
    const int f = t & 127;
    const int kq = t >> 7;
    if (blockIdx.x < NG_) {
        // ---------------- lin1 ----------------
        const int row0 = blockIdx.x * 4;
        const int b  = row0 >> 9;
        const int n0 = row0 & 511;
        sH[kq][f] = H[(size_t)(row0 + kq) * F_ + f];
        __syncthreads();
        float accA[4] = {0.f,0.f,0.f,0.f}, accB[4] = {0.f,0.f,0.f,0.f};
        const int k0 = kq * 32;
        #pragma unroll 4
        for (int k = k0; k < k0 + 32; ++k) {
            const float wa = dW1[(size_t)k * F_ + f];
            const float wb = dW1[(size_t)(F_ + k) * F_ + f];
            #pragma unroll
            for (int r = 0; r < 4; ++r) {
                accA[r] = fmaf(sH[r][k], wa, accA[r]);
                accB[r] = fmaf(sH[r][k], wb, accB[r]);
            }
        }
        if (kq > 0) {
            #pragma unroll
            for (int r = 0; r < 4; ++r) {
                sPA[kq - 1][r][f] = accA[r];
                sPB[kq - 1][r][f] = accB[r];
            }
        }
        __syncthreads();
        if (kq == 0) {
            const float bias = db1[f];
            float bsum[4];
            #pragma unroll
            for (int r = 0; r < 4; ++r) {
                const float av = accA[r] + sPA[0][r][f] + sPA[1][r][f]
                               + sPA[2][r][f] + bias;
                Hi [(size_t)(row0 + r) * F_ + f] = av;
                EHi[(size_t)(row0 + r) * F_ + f] = __expf(av);
                bsum[r] = accB[r] + sPB[0][r][f] + sPB[1][r][f] + sPB[2][r][f];
            }
            float4 hv;
            hv.x = bsum[0]; hv.y = bsum[1]; hv.z = bsum[2]; hv.w = bsum[3];
            *reinterpret_cast<float4*>(HjT + ((size_t)b * F_ + f) * N_ + n0) = hv;
        }
    } else {
        // ---------------- colsum partial ----------------
        const int bx = blockIdx.x - NG_;   // 0..31
        const int b  = bx >> 3;
        const int e  = bx & 7;             // batch-eighth (64 rows)
        float s = 0.f;
        const float* hp = H + ((size_t)b * N_ + e * 64 + kq * 16) * F_ + f;
        #pragma unroll 4
        for (int jj = 0; jj < 16; ++jj) s += hp[(size_t)jj * F_];
        sH[kq][f] = s;
        __syncthreads();
        if (kq == 0)
            csp[((size_t)b * 8 + e) * F_ + f] =
                sH[0][f] + sH[1][f] + sH[2][f] + sH[3][f];
    }
}

// ---------------------------------------------------------------------------
// Kernel 2: score. 4 rows/block, 512 blocks x 512 thr (thread = j).
// elu(hi+hj) = med3(x, Ei*Ej-1, 0): 4 ops/elem; exp shared by 4 rows.
// Also emits per-row: maxc (sigmoid of max connected logit), deg
// (popcount of A>0), zmask (per-wave ballot of A<=0, for nf exceptions).
// ---------------------------------------------------------------------------
__global__ __launch_bounds__(512, 4) void k_score(
    const float* __restrict__ Hi, const float* __restrict__ EHi,
    const float* __restrict__ HjT, const float* __restrict__ A,
    const float* __restrict__ dW2, const float* __restrict__ db2,
    float* __restrict__ maxcv, float* __restrict__ degv,
    unsigned long long* __restrict__ zmask, float* __restrict__ maskout) {
    __shared__ float4 sU[32][9];          // [quad][0..3]=hi rows,[4..7]=Ei,[8]=w
    __shared__ float red_mx[8][4];
    __shared__ int   red_cnt[8][4];
    const int t = threadIdx.x;            // == j
    const int lane = t & 63;
    const int w = t >> 6;                 // wave 0..7
    const int bi0 = blockIdx.x * 4;
    const int b = bi0 >> 9;

    if (t < 288) {
        const int q  = t / 9;
        const int sl = t - q * 9;
        const float* src = (sl < 4) ? (Hi  + (size_t)(bi0 + sl)     * F_ + 4 * q)
                         : (sl < 8) ? (EHi + (size_t)(bi0 + sl - 4) * F_ + 4 * q)
                                    : (dW2 + 4 * q);
        sU[q][sl] = *reinterpret_cast<const float4*>(src);
    }
    float a_r[4];
    #pragma unroll
    for (int r = 0; r < 4; ++r) a_r[r] = A[(size_t)(bi0 + r) * N_ + t];

    const float* __restrict__ hjp = HjT + (size_t)b * F_ * N_ + t;
    float hjA[4], hjB[4];
    #pragma unroll
    for (int s = 0; s < 4; ++s) hjA[s] = hjp[(size_t)s * N_];
    __syncthreads();

    float acc0 = 0.f, acc1 = 0.f, acc2 = 0.f, acc3 = 0.f;
    auto compQ = [&](int q, const float (&hjv)[4]) {
        const float4 h0 = sU[q][0], h1 = sU[q][1], h2 = sU[q][2], h3 = sU[q][3];
        const float4 e0 = sU[q][4], e1 = sU[q][5], e2 = sU[q][6], e3 = sU[q][7];
        const float4 wq = sU[q][8];
        const float* h0p = &h0.x; const float* h1p = &h1.x;
        const float* h2p = &h2.x; const float* h3p = &h3.x;
        const float* e0p = &e0.x; const float* e1p = &e1.x;
        const float* e2p = &e2.x; const float* e3p = &e3.x;
        const float* wqp = &wq.x;
        #pragma unroll
        for (int s = 0; s < 4; ++s) {
            const float hj = hjv[s];
            const float ej = __expf(hj);
            const float wv = wqp[s];
            acc0 = fmaf(__builtin_amdgcn_fmed3f(h0p[s] + hj,
                        fmaf(e0p[s], ej, -1.f), 0.f), wv, acc0);
            acc1 = fmaf(__builtin_amdgcn_fmed3f(h1p[s] + hj,
                        fmaf(e1p[s], ej, -1.f), 0.f), wv, acc1);
            acc2 = fmaf(__builtin_amdgcn_fmed3f(h2p[s] + hj,
                        fmaf(e2p[s], ej, -1.f), 0.f), wv, acc2);
            acc3 = fmaf(__builtin_amdgcn_fmed3f(h3p[s] + hj,
                        fmaf(e3p[s], ej, -1.f), 0.f), wv, acc3);
        }
    };
    auto loadhj = [&](int q, float (&buf)[4]) {
        #pragma unroll
        for (int s = 0; s < 4; ++s) buf[s] = hjp[(size_t)(4 * q + s) * N_];
    };
    for (int q = 0; q < 32; q += 2) {
        loadhj(q + 1, hjB);
        compQ(q, hjA);
        if (q + 2 < 32) loadhj(q + 2, hjA);
        compQ(q + 1, hjB);
    }

    float accv[4] = {acc0, acc1, acc2, acc3};
    #pragma unroll
    for (int r = 0; r < 4; ++r) {
        const float a = a_r[r];
        float mx = (a > 0.1f) ? accv[r] : -INFINITY;
        #pragma unroll
        for (int off = 1; off < 64; off <<= 1)
            mx = fmaxf(mx, __shfl_xor(mx, off));
        const unsigned long long pos = __ballot(a > 0.f);
        const unsigned long long zb  = __ballot(a <= 0.f);
        if (lane == 0) {
            red_mx[w][r]  = mx;
            red_cnt[w][r] = (int)__popcll(pos);
            zmask[(size_t)(bi0 + r) * 8 + w] = zb;
        }
    }
    __syncthreads();
    if (t < 4) {
        float m = -INFINITY; int c = 0;
        #pragma unroll
        for (int ww = 0; ww < 8; ++ww) {
            m = fmaxf(m, red_mx[ww][t]);
            c += red_cnt[ww][t];
        }
        const float mc = (m > -INFINITY)
                       ? 1.f / (1.f + __expf(-(m + db2[0]))) : 0.f;
        maxcv[bi0 + t] = mc;
        degv[bi0 + t]  = (float)c;
        maskout[bi0 + t] = (mc > 0.5f) ? 1.f : 0.f;
    }
}

// ---------------------------------------------------------------------------
// Kernel 3: row MLP. 4 rows/block, 512 blocks x 512 thr; f=t&127, kq=t>>7.
// nf = (colsum - sum of A<=0 exception rows) / deg — exceptions from zmask,
// uniform control flow, usually zero iterations.
// ---------------------------------------------------------------------------
__global__ __launch_bounds__(512, 4) void k_mlp(
    const float* __restrict__ H, const float* __restrict__ csp,
    const unsigned long long* __restrict__ zmask,
    const float* __restrict__ degv, const float* __restrict__ maxcv,
    const float* __restrict__ rW1, const float* __restrict__ rb1,
    const float* __restrict__ rW2, const float* __restrict__ rb2,
    float* __restrict__ out) {
    __shared__ float sC[4][260];
    __shared__ float sP[3][4][F_];
    __shared__ float sL1[4][F_];
    __shared__ float sMC[4], sDegF[4];
    const int t  = threadIdx.x;
    const int f  = t & 127;
    const int kq = t >> 7;
    const int row0 = blockIdx.x * 4;
    const int b = row0 >> 9;

    {   // stage H + assembled nf (thread's row = kq)
        const int row = row0 + kq;
        sC[kq][f] = H[(size_t)row * F_ + f];
        float cs = 0.f;
        #pragma unroll
        for (int e = 0; e < 8; ++e)
            cs += csp[((size_t)b * 8 + e) * F_ + f];
        #pragma unroll
        for (int wv = 0; wv < 8; ++wv) {
            unsigned long long zb = zmask[(size_t)row * 8 + wv];
            while (zb) {                    // uniform loop; empty in practice
                const int j = __ffsll(zb) - 1;
                zb &= zb - 1;
                cs -= H[((size_t)b * N_ + wv * 64 + j) * F_ + f];
            }
        }
        sC[kq][F_ + f] = cs / fmaxf(degv[row], 1.f);
    }
    if (t < 4) {
        sMC[t]   = maxcv[row0 + t];
        sDegF[t] = degv[row0 + t];
    }
    __syncthreads();

    // ---- layer 1 ----
    float macc[4];
    {
        const float bias = rb1[f];
        #pragma unroll
        for (int r = 0; r < 4; ++r) macc[r] = (kq == 0) ? bias : 0.f;
    }
    const int k0 = kq * 64;
    #pragma unroll 4
    for (int k = k0; k < k0 + 64; ++k) {
        const float wv = rW1[(size_t)k * F_ + f];
        #pragma unroll
        for (int r = 0; r < 4; ++r) macc[r] = fmaf(sC[r][k], wv, macc[r]);
    }
    if (kq == 3) {
        const float w256 = rW1[(size_t)256 * F_ + f];
        #pragma unroll
        for (int r = 0; r < 4; ++r) macc[r] = fmaf(sMC[r], w256, macc[r]);
    }
    if (kq > 0) {
        #pragma unroll
        for (int r = 0; r < 4; ++r) sP[kq - 1][r][f] = macc[r];
    }
    __syncthreads();
    if (kq == 0) {
        #pragma unroll
        for (int r = 0; r < 4; ++r)
            sL1[r][f] = elu_f(macc[r] + sP[0][r][f] + sP[1][r][f] + sP[2][r][f]);
    }
    __syncthreads();

    // ---- layer 2 ----
    float macc2[4];
    {
        const float bias2 = rb2[f];
        #pragma unroll
        for (int r = 0; r < 4; ++r) macc2[r] = (kq == 0) ? bias2 : 0.f;
    }
    const int m0k = kq * 32;
    #pragma unroll 4
    for (int k = m0k; k < m0k + 32; ++k) {
        const float wv = rW2[(size_t)k * F_ + f];
        #pragma unroll
        for (int r = 0; r < 4; ++r) macc2[r] = fmaf(sL1[r][k], wv, macc2[r]);
    }
    if (kq > 0) {
        #pragma unroll
        for (int r = 0; r < 4; ++r) sP[kq - 1][r][f] = macc2[r];
    }
    __syncthreads();
    if (kq == 0) {
        #pragma unroll
        for (int r = 0; r < 4; ++r) {
            const int row = row0 + r;
            const float res = macc2[r] + sP[0][r][f] + sP[1][r][f] + sP[2][r][f];
            const bool upd = (sMC[r] > 0.5f) && (sDegF[r] > 0.f);
            out[(size_t)row * F_ + f] = upd ? res : sC[r][f];
        }
    }
}

// ---------------------------------------------------------------------------
extern "C" void kernel_launch(void* const* d_in, const int* in_sizes, int n_in,
                              void* d_out, int out_size, void* d_ws, size_t ws_size,
                              hipStream_t stream) {
    const float* H   = (const float*)d_in[0];
    const float* A   = (const float*)d_in[1];
    const float* dW1 = (const float*)d_in[2];
    const float* db1 = (const float*)d_in[3];
    const float* dW2 = (const float*)d_in[4];
    const float* db2 = (const float*)d_in[5];
    const float* rW1 = (const float*)d_in[6];
    const float* rb1 = (const float*)d_in[7];
    const float* rW2 = (const float*)d_in[8];
    const float* rb2 = (const float*)d_in[9];

    float* ws   = (float*)d_ws;
    float* Hi   = ws;                        // [BN][F]
    float* EHi  = Hi   + BN_ * F_;           // [BN][F]
    float* HjT  = EHi  + BN_ * F_;           // [B][F][N]
    float* csp  = HjT  + BN_ * F_;           // [B][8][F] colsum partials
    float* degv = csp  + B_ * 8 * F_;        // [BN]
    float* maxc = degv + BN_;                // [BN]
    unsigned long long* zmask =
        (unsigned long long*)(maxc + BN_);   // [BN][8] (8B-aligned: offset even)

    float* out      = (float*)d_out;         // [BN][F]
    float* mask_out = out + BN_ * F_;        // [BN]

    k_pre  <<<NG_ + 32, 512, 0, stream>>>(H, dW1, db1, Hi, EHi, HjT, csp);
    k_score<<<NG_, 512, 0, stream>>>(Hi, EHi, HjT, A, dW2, db2,
                                     maxc, degv, zmask, mask_out);
    k_mlp  <<<NG_, 512, 0, stream>>>(H, csp, zmask, degv, maxc,
                                     rW1, rb1, rW2, rb2, out);
}